// Round 13
// baseline (648.227 us; speedup 1.0000x reference)
//
#include <hip/hip_runtime.h>

#define HID 50
#define FOURH 200
#define TSTEPS 2048
#define NBATCH 1024

#define LOG2E 1.44269504f

typedef _Float16 v2h __attribute__((ext_vector_type(2)));

__device__ __forceinline__ float frcp(float x)  { return __builtin_amdgcn_rcpf(x); }
__device__ __forceinline__ float fexp2(float x) { return __builtin_amdgcn_exp2f(x); }
__device__ __forceinline__ v2h bc_v2h(unsigned int u) {
    return __builtin_bit_cast(v2h, u);
}

// Issue model v3 (fits r0..r12 within ~4%): lone wave, dur = plainVALU*4cy +
// trans*16cy; every instruction issue costs 4cy regardless of pipe. r12 =
// ~750cy/step. This round cuts issue count, not latency:
//  - HYBRID h BROADCAST: pairs 0..11 via DPP row_shl:1 + cvt_pkrtz + 12
//    v_readlane (48cy); pairs 12..24 via LDS broadcast (1 ds_write_b16 at
//    step end + 3 ds_read_b128 + 1 ds_read_b32 at step start, uniform addr).
//    The 48 RL-fed dots (~192cy) cover the ~120cy LDS latency -> ~37cy saved
//    vs 25 readlanes. Same-wave DS ordering guarantees write->read visibility
//    (r0-proven).
//  - MERGED fg-rcp: cs_new = cs/(1+ef) + num1/den1
//                          = (cs*den1 + num1*a3) * rcp(den1*a3)
//    -> one rcp for the whole cell update. Trans 8 -> 7 (5 exp2 + 2 rcp).
//  - Retained: single 25-dot chain per gate w/ x+bias init; i/f/o weights
//    pre-scaled -L (sigmoid sign), g pre-scaled +2L (tanh form); cell in
//    2L-space; h = (ec-1)/[(1+eo)(1+ec)] one-rcp form; x via float4 / 4 steps.
// Budget ~670cy/step -> predict 575-615us.
__global__ __launch_bounds__(64, 1)
void lstm_hyb_kernel(const float* __restrict__ x,
                     const float* __restrict__ Wx,
                     const float* __restrict__ Wh,
                     const float* __restrict__ bias,
                     const float* __restrict__ Wd,
                     const float* __restrict__ bd,
                     float* __restrict__ out) {
    const int b    = blockIdx.x;
    const int lane = threadIdx.x;
    const int lc   = (lane < HID) ? lane : (HID - 1);

    __shared__ __align__(16) float    xs[TSTEPS + 8];
    __shared__ __align__(16) _Float16 hbuf[80];  // [0..49] h, [64..77] scratch

    // Stage x (coalesced float4 loads).
    const float4* xb4 = (const float4*)(x + (size_t)b * TSTEPS);
    float4* xs4 = (float4*)xs;
    #pragma unroll
    for (int i = lane; i < TSTEPS / 4; i += 64) xs4[i] = xb4[i];
    if (lane < 8) xs[TSTEPS + lane] = 0.0f;
    for (int i = lane; i < 80; i += 64) hbuf[i] = (_Float16)0.0f;

    // Recurrent weights packed along k as half2 (25 pairs), scales folded:
    // i/f/o -> -L (sigmoid sign), g -> +2L (tanh form).
    const float SNEG = -LOG2E;
    const float S2L  = 2.0f * LOG2E;
    v2h wi[25], wf[25], wg[25], wo[25];
    #pragma unroll
    for (int k2 = 0; k2 < 25; ++k2) {
        const float* r0 = Wh + (2 * k2) * FOURH;
        const float* r1 = Wh + (2 * k2 + 1) * FOURH;
        wi[k2] = v2h{(_Float16)(SNEG * r0[lc]),           (_Float16)(SNEG * r1[lc])};
        wf[k2] = v2h{(_Float16)(SNEG * r0[HID + lc]),     (_Float16)(SNEG * r1[HID + lc])};
        wg[k2] = v2h{(_Float16)(S2L  * r0[2 * HID + lc]), (_Float16)(S2L  * r1[2 * HID + lc])};
        wo[k2] = v2h{(_Float16)(SNEG * r0[3 * HID + lc]), (_Float16)(SNEG * r1[3 * HID + lc])};
    }
    const float wx_i = SNEG * Wx[lc],           b_i = SNEG * bias[lc];
    const float wx_f = SNEG * Wx[HID + lc],     b_f = SNEG * bias[HID + lc];
    const float wx_g = S2L  * Wx[2 * HID + lc], b_g = S2L  * bias[2 * HID + lc];
    const float wx_o = SNEG * Wx[3 * HID + lc], b_o = SNEG * bias[3 * HID + lc];

    // Branchless h-write slot: real units -> [0..49], dup lanes -> [64..77].
    const int widx = (lane < HID) ? lane : (lane + 14);

    float cs = 0.0f;   // 2L-scaled cell state
    float h  = 0.0f;
    __syncthreads();   // staging + hbuf zero visible

    const float4* xsv = (const float4*)xs;
    float4 xq = xsv[0];

    for (int tb = 0; tb < TSTEPS; tb += 4) {
        const float4 xq_next = xsv[(tb >> 2) + 1];   // prefetch next block

        #pragma unroll
        for (int s = 0; s < 4; ++s) {
            const float xt = (s == 0) ? xq.x : (s == 1) ? xq.y
                           : (s == 2) ? xq.z : xq.w;

            // --- LDS broadcast of pairs 12..24 (h[24..49]), issued FIRST so
            // the 48 RL-fed dots below cover the latency.
            const uint4    q0  = *(const uint4*)(hbuf + 24);  // h[24..31]
            const uint4    q1  = *(const uint4*)(hbuf + 32);  // h[32..39]
            const uint4    q2  = *(const uint4*)(hbuf + 40);  // h[40..47]
            const unsigned q3  = *(const unsigned*)(hbuf + 48); // h[48..49]
            const unsigned hl[13] = {q0.x, q0.y, q0.z, q0.w,
                                     q1.x, q1.y, q1.z, q1.w,
                                     q2.x, q2.y, q2.z, q2.w, q3};

            // --- RL broadcast of pairs 0..11: DPP neighbor + pkrtz + 12 RL.
            const int hi32 = __builtin_bit_cast(int, h);
            const int hn32 = __builtin_amdgcn_update_dpp(
                0, hi32, 0x101 /*row_shl:1*/, 0xf, 0xf, true);
            const float hn = __builtin_bit_cast(float, hn32);
            const unsigned hp =
                __builtin_bit_cast(unsigned, __builtin_amdgcn_cvt_pkrtz(h, hn));
            unsigned sh[12];
            #pragma unroll
            for (int k = 0; k < 12; ++k)
                sh[k] = (unsigned)__builtin_amdgcn_readlane((int)hp, 2 * k);

            // --- 4 single dot chains; RL pairs first (cover LDS), LDS pairs after.
            float zi = fmaf(xt, wx_i, b_i);
            float zg = fmaf(xt, wx_g, b_g);
            float zf = fmaf(xt, wx_f, b_f);
            #pragma unroll
            for (int j = 0; j < 12; ++j) {
                const v2h hj = bc_v2h(sh[j]);
                zi = __builtin_amdgcn_fdot2(wi[j], hj, zi, false);
                zg = __builtin_amdgcn_fdot2(wg[j], hj, zg, false);
                zf = __builtin_amdgcn_fdot2(wf[j], hj, zf, false);
            }
            #pragma unroll
            for (int j = 0; j < 13; ++j) {
                const v2h hj = bc_v2h(hl[j]);
                zi = __builtin_amdgcn_fdot2(wi[12 + j], hj, zi, false);
                zg = __builtin_amdgcn_fdot2(wg[12 + j], hj, zg, false);
                zf = __builtin_amdgcn_fdot2(wf[12 + j], hj, zf, false);
            }
            const float ei = fexp2(zi);                 // e^{-z_i}
            const float eg = fexp2(zg);                 // e^{2 z_g}
            const float ef = fexp2(zf);                 // e^{-z_f}

            // Merged cell update: one rcp for ig*gg2L AND fg.
            const float a1   = 1.0f + ei;
            const float a2   = 1.0f + eg;
            const float den1 = a1 * a2;
            const float num1 = fmaf(eg, S2L, -S2L);     // 2L*(eg-1)
            const float a3   = 1.0f + ef;
            const float dd   = den1 * a3;
            const float rr   = frcp(dd);
            const float m1   = num1 * a3;
            const float tnum = fmaf(cs, den1, m1);
            const float cs_new = tnum * rr;             // 2L * c
            const float ec = fexp2(cs_new);             // e^{2c} (under o-dots)

            // --- gate o (dots hide the ec latency).
            float zo = fmaf(xt, wx_o, b_o);
            #pragma unroll
            for (int j = 0; j < 12; ++j)
                zo = __builtin_amdgcn_fdot2(wo[j], bc_v2h(sh[j]), zo, false);
            #pragma unroll
            for (int j = 0; j < 13; ++j)
                zo = __builtin_amdgcn_fdot2(wo[12 + j], bc_v2h(hl[j]), zo, false);
            const float eo = fexp2(zo);                 // e^{-z_o}

            // h = og * tanh(c) = (ec-1) / [(1+eo)(1+ec)]  (one rcp)
            const float a4   = 1.0f + eo;
            const float a5   = 1.0f + ec;
            const float den2 = a4 * a5;
            const float r2   = frcp(den2);
            const float num2 = ec - 1.0f;
            cs = cs_new;
            h  = num2 * r2;

            hbuf[widx] = (_Float16)h;   // same-wave DS ordering; read next step
        }

        xq = xq_next;
    }

    // out[b] = h_T . Wd + bd
    float v = (lane < HID) ? h * Wd[lane] : 0.0f;
    #pragma unroll
    for (int off = 32; off > 0; off >>= 1) v += __shfl_down(v, off);
    if (lane == 0) out[b] = v + bd[0];
}

extern "C" void kernel_launch(void* const* d_in, const int* in_sizes, int n_in,
                              void* d_out, int out_size, void* d_ws, size_t ws_size,
                              hipStream_t stream) {
    const float* x    = (const float*)d_in[0];  // [1024, 2048, 1]
    const float* Wx   = (const float*)d_in[1];  // [1, 200]
    const float* Wh   = (const float*)d_in[2];  // [50, 200]
    const float* bias = (const float*)d_in[3];  // [200]
    const float* Wd   = (const float*)d_in[4];  // [50, 1]
    const float* bd   = (const float*)d_in[5];  // [1]
    float* out = (float*)d_out;                 // [1024, 1]

    lstm_hyb_kernel<<<dim3(NBATCH), dim3(64), 0, stream>>>(
        x, Wx, Wh, bias, Wd, bd, out);
}

// Round 14
// 644.842 us; speedup vs baseline: 1.0052x; 1.0052x over previous
//
#include <hip/hip_runtime.h>

#define HID 50
#define FOURH 200
#define TSTEPS 2048
#define NBATCH 1024

#define LOG2E 1.44269504f

typedef _Float16 v2h __attribute__((ext_vector_type(2)));
typedef float    f32x2 __attribute__((ext_vector_type(2)));

__device__ __forceinline__ float frcp(float x)  { return __builtin_amdgcn_rcpf(x); }
__device__ __forceinline__ float fexp2(float x) { return __builtin_amdgcn_exp2f(x); }
__device__ __forceinline__ v2h bc_v2h(unsigned int u) {
    return __builtin_bit_cast(v2h, u);
}

// Issue model v3 (fits r0..r13): lone wave, dur = plainVALU*4cy + trans*16cy
// + small stall. r12 = 750cy/step. r13 lesson: LDS h-broadcast adds ~80cy
// critical-path stall -> all-readlane broadcast is the right structure.
// This round, arithmetic trims only on the r12 base:
//  - MERGED fg-rcp (r13-validated numerics): cs_new = (cs*den1 + num1*a3) *
//    rcp(den1*a3) -> one rcp for the cell update. Trans 8 -> 7.
//  - PACKED PAIRS: inits (zi,zf) and (zg,zo) as f32x2 fma -> v_pk_fma_f32;
//    (a1,a2) = 1 + (ei,eg) packed add; (den1,m?) where possible.
//  - PARALLEL NEIGHBOR-h: DPP num2,r2 separately; hn = num2n*r2n runs
//    concurrently with h = num2*r2 (cuts the serial broadcast head).
//  - Retained: single 25-dot chain per gate; i/f/o weights * -L, g * +2L;
//    cell in 2L-space; h=(ec-1)/[(1+eo)(1+ec)] one-rcp form; x float4/4 steps.
__global__ __launch_bounds__(64, 1)
void lstm_pk_kernel(const float* __restrict__ x,
                    const float* __restrict__ Wx,
                    const float* __restrict__ Wh,
                    const float* __restrict__ bias,
                    const float* __restrict__ Wd,
                    const float* __restrict__ bd,
                    float* __restrict__ out) {
    const int b    = blockIdx.x;
    const int lane = threadIdx.x;
    const int lc   = (lane < HID) ? lane : (HID - 1);

    __shared__ __align__(16) float xs[TSTEPS + 8];

    // Stage x (coalesced float4 loads).
    const float4* xb4 = (const float4*)(x + (size_t)b * TSTEPS);
    float4* xs4 = (float4*)xs;
    #pragma unroll
    for (int i = lane; i < TSTEPS / 4; i += 64) xs4[i] = xb4[i];
    if (lane < 8) xs[TSTEPS + lane] = 0.0f;

    // Recurrent weights packed along k as half2 (25 pairs), scales folded:
    // i/f/o -> -L (sigmoid sign), g -> +2L (tanh form).
    const float SNEG = -LOG2E;
    const float S2L  = 2.0f * LOG2E;
    v2h wi[25], wf[25], wg[25], wo[25];
    #pragma unroll
    for (int k2 = 0; k2 < 25; ++k2) {
        const float* r0 = Wh + (2 * k2) * FOURH;
        const float* r1 = Wh + (2 * k2 + 1) * FOURH;
        wi[k2] = v2h{(_Float16)(SNEG * r0[lc]),           (_Float16)(SNEG * r1[lc])};
        wf[k2] = v2h{(_Float16)(SNEG * r0[HID + lc]),     (_Float16)(SNEG * r1[HID + lc])};
        wg[k2] = v2h{(_Float16)(S2L  * r0[2 * HID + lc]), (_Float16)(S2L  * r1[2 * HID + lc])};
        wo[k2] = v2h{(_Float16)(SNEG * r0[3 * HID + lc]), (_Float16)(SNEG * r1[3 * HID + lc])};
    }
    // Packed (i,f) and (g,o) x-path weights/biases for pk inits.
    const f32x2 wx_if = {SNEG * Wx[lc],           SNEG * Wx[HID + lc]};
    const f32x2 b_if  = {SNEG * bias[lc],         SNEG * bias[HID + lc]};
    const f32x2 wx_go = {S2L  * Wx[2 * HID + lc], SNEG * Wx[3 * HID + lc]};
    const f32x2 b_go  = {S2L  * bias[2 * HID + lc], SNEG * bias[3 * HID + lc]};

    float cs = 0.0f;   // 2L-scaled cell state
    float h  = 0.0f;
    float hn = 0.0f;   // neighbor's h (maintained in parallel)
    __syncthreads();   // x staging visible

    const float4* xsv = (const float4*)xs;
    float4 xq = xsv[0];

    for (int tb = 0; tb < TSTEPS; tb += 4) {
        const float4 xq_next = xsv[(tb >> 2) + 1];   // prefetch next block

        #pragma unroll
        for (int s = 0; s < 4; ++s) {
            const float xt = (s == 0) ? xq.x : (s == 1) ? xq.y
                           : (s == 2) ? xq.z : xq.w;

            // --- h broadcast: pkrtz(h, hn) -> 25 readlane -> SGPR operands.
            const unsigned hp =
                __builtin_bit_cast(unsigned, __builtin_amdgcn_cvt_pkrtz(h, hn));
            unsigned sh[25];
            #pragma unroll
            for (int k = 0; k < 25; ++k)
                sh[k] = (unsigned)__builtin_amdgcn_readlane((int)hp, 2 * k);

            // --- packed inits, then 4 single dot chains (25 fdot2 each).
            const f32x2 xt2 = {xt, xt};
            const f32x2 zif0 = xt2 * wx_if + b_if;   // v_pk_fma_f32
            const f32x2 zgo0 = xt2 * wx_go + b_go;   // v_pk_fma_f32
            float zi = zif0.x, zf = zif0.y, zg = zgo0.x, zo = zgo0.y;

            #pragma unroll
            for (int j = 0; j < 25; ++j) {
                const v2h hj = bc_v2h(sh[j]);
                zi = __builtin_amdgcn_fdot2(wi[j], hj, zi, false);
                zg = __builtin_amdgcn_fdot2(wg[j], hj, zg, false);
                zf = __builtin_amdgcn_fdot2(wf[j], hj, zf, false);
            }
            const float ei = fexp2(zi);                 // e^{-z_i}
            const float eg = fexp2(zg);                 // e^{2 z_g}
            const float ef = fexp2(zf);                 // e^{-z_f}

            // Merged cell update: one rcp for ig*gg2L AND fg.
            const f32x2 eig = {ei, eg};
            const f32x2 a12 = eig + f32x2{1.0f, 1.0f};  // v_pk_add_f32
            const float den1 = a12.x * a12.y;
            const float num1 = fmaf(eg, S2L, -S2L);     // 2L*(eg-1)
            const float a3   = 1.0f + ef;
            const float dd   = den1 * a3;
            const float rr   = frcp(dd);
            const float m1   = num1 * a3;
            const float tnum = fmaf(cs, den1, m1);
            const float cs_new = tnum * rr;             // 2L * c
            const float ec = fexp2(cs_new);             // e^{2c} (under o-dots)

            // --- gate o (dots hide the ec latency).
            float zov = zo;
            #pragma unroll
            for (int j = 0; j < 25; ++j)
                zov = __builtin_amdgcn_fdot2(wo[j], bc_v2h(sh[j]), zov, false);
            const float eo = fexp2(zov);                // e^{-z_o}

            // h = og * tanh(c) = (ec-1) / [(1+eo)(1+ec)]  (one rcp)
            const f32x2 eoc = {eo, ec};
            const f32x2 a45 = eoc + f32x2{1.0f, 1.0f};  // v_pk_add_f32
            const float den2 = a45.x * a45.y;
            const float r2   = frcp(den2);
            const float num2 = ec - 1.0f;
            cs = cs_new;
            h  = num2 * r2;

            // Neighbor h in parallel: DPP the two factors, multiply locally
            // (hn-mul runs concurrently with the h-mul, off the critical path).
            const int n2 = __builtin_amdgcn_update_dpp(
                0, __builtin_bit_cast(int, num2), 0x101, 0xf, 0xf, true);
            const int r2n = __builtin_amdgcn_update_dpp(
                0, __builtin_bit_cast(int, r2), 0x101, 0xf, 0xf, true);
            hn = __builtin_bit_cast(float, n2) * __builtin_bit_cast(float, r2n);
        }

        xq = xq_next;
    }

    // out[b] = h_T . Wd + bd
    float v = (lane < HID) ? h * Wd[lane] : 0.0f;
    #pragma unroll
    for (int off = 32; off > 0; off >>= 1) v += __shfl_down(v, off);
    if (lane == 0) out[b] = v + bd[0];
}

extern "C" void kernel_launch(void* const* d_in, const int* in_sizes, int n_in,
                              void* d_out, int out_size, void* d_ws, size_t ws_size,
                              hipStream_t stream) {
    const float* x    = (const float*)d_in[0];  // [1024, 2048, 1]
    const float* Wx   = (const float*)d_in[1];  // [1, 200]
    const float* Wh   = (const float*)d_in[2];  // [50, 200]
    const float* bias = (const float*)d_in[3];  // [200]
    const float* Wd   = (const float*)d_in[4];  // [50, 1]
    const float* bd   = (const float*)d_in[5];  // [1]
    float* out = (float*)d_out;                 // [1024, 1]

    lstm_pk_kernel<<<dim3(NBATCH), dim3(64), 0, stream>>>(
        x, Wx, Wh, bias, Wd, bd, out);
}